// Round 11
// baseline (132.892 us; speedup 1.0000x reference)
//
#include <hip/hip_runtime.h>
#include <hip/hip_bf16.h>
#include <stdint.h>

#define B_ 4
#define C_ 256
#define N_ 4096
#define D_ 32
#define KT 256    // keys per inner iteration
#define KH 2048   // keys per block (k-split half)

typedef __bf16 bf16_t;
typedef __bf16 bf16x4_t __attribute__((ext_vector_type(4)));
typedef __bf16 bf16x8_t __attribute__((ext_vector_type(8)));
typedef float  f32x4    __attribute__((ext_vector_type(4)));

// ---------------------------------------------------------------------------
// fused cast: blocks <1024 transpose+cast x -> xbT bf16 [B][N][C];
// blocks >=1024 cast W (wq|wk|wv) -> Wb bf16 [320][256]
// ---------------------------------------------------------------------------
__global__ __launch_bounds__(256) void cast_kernel(
    const float* __restrict__ x,
    const float* __restrict__ wq, const float* __restrict__ wk,
    const float* __restrict__ wv,
    bf16_t* __restrict__ xbT, bf16_t* __restrict__ Wb)
{
  const int bid = blockIdx.x;
  const int t = threadIdx.x;
  if (bid >= 1024) {
    const int gr = bid - 1024;   // 0..319
    float v;
    if (gr < 32)      v = wq[gr * C_ + t];
    else if (gr < 64) v = wk[(gr - 32) * C_ + t];
    else              v = wv[(gr - 64) * C_ + t];
    Wb[gr * C_ + t] = (bf16_t)v;
    return;
  }
  __shared__ float xs[64][65];
  const int n0 = (bid & 63) * 64;
  const int c0 = ((bid >> 6) & 3) * 64;
  const int b  = bid >> 8;

  const int lr = t >> 4;
  const int lc = (t & 15) * 4;
#pragma unroll
  for (int i = 0; i < 4; ++i) {
    const f32x4 v = *(const f32x4*)(x + ((size_t)(b * C_ + c0 + lr + i * 16)) * N_ + n0 + lc);
    xs[lr + i * 16][lc + 0] = v[0];
    xs[lr + i * 16][lc + 1] = v[1];
    xs[lr + i * 16][lc + 2] = v[2];
    xs[lr + i * 16][lc + 3] = v[3];
  }
  __syncthreads();
  const int nr = t >> 2;
  const int cb = (t & 3) * 16;
  bf16_t tmp[16];
#pragma unroll
  for (int j = 0; j < 16; ++j) tmp[j] = (bf16_t)xs[cb + j][nr];
  bf16_t* dst = xbT + ((size_t)(b * N_ + n0 + nr)) * C_ + c0 + cb;
  *(bf16x8_t*)dst       = *(bf16x8_t*)&tmp[0];
  *(bf16x8_t*)(dst + 8) = *(bf16x8_t*)&tmp[8];
}

// ---------------------------------------------------------------------------
// Projection GEMM: Wb[320][256] x xbT^T -> Q/K/V bf16 MFMA, no LDS.
// grid 256, n-tile 64. Q pre-scaled by log2(e) (exp2-domain softmax).
// ---------------------------------------------------------------------------
__global__ __launch_bounds__(256) void proj_kernel(
    const bf16_t* __restrict__ Wb, const bf16_t* __restrict__ xbT,
    const float* __restrict__ bq, const float* __restrict__ bk,
    const float* __restrict__ bv,
    bf16_t* __restrict__ Qh, bf16_t* __restrict__ Kh, bf16_t* __restrict__ Vh)
{
  const int bi = blockIdx.x;
  const int b  = bi & 3;
  const int n0 = (bi >> 2) * 64;
  const int t = threadIdx.x, w = t >> 6, lane = t & 63;
  const int l4 = lane >> 4, lm = lane & 15;

  const f32x4 z4 = {0.f, 0.f, 0.f, 0.f};
  f32x4 acc[5][4];
#pragma unroll
  for (int rt = 0; rt < 5; ++rt)
#pragma unroll
    for (int ct = 0; ct < 4; ++ct) acc[rt][ct] = z4;

#pragma unroll 1
  for (int k0 = 0; k0 < C_; k0 += 64) {
    bf16x8_t af[5][2], bfr[4][2];
#pragma unroll
    for (int rt = 0; rt < 5; ++rt)
#pragma unroll
      for (int kc = 0; kc < 2; ++kc)
        af[rt][kc] = *(const bf16x8_t*)(Wb + (size_t)(w * 80 + rt * 16 + lm) * C_ + k0 + kc * 32 + l4 * 8);
#pragma unroll
    for (int ct = 0; ct < 4; ++ct)
#pragma unroll
      for (int kc = 0; kc < 2; ++kc)
        bfr[ct][kc] = *(const bf16x8_t*)(xbT + ((size_t)(b * N_ + n0 + ct * 16 + lm)) * C_ + k0 + kc * 32 + l4 * 8);
#pragma unroll
    for (int rt = 0; rt < 5; ++rt)
#pragma unroll
      for (int ct = 0; ct < 4; ++ct)
#pragma unroll
        for (int kc = 0; kc < 2; ++kc)
          acc[rt][ct] = __builtin_amdgcn_mfma_f32_16x16x32_bf16(af[rt][kc], bfr[ct][kc], acc[rt][ct], 0, 0, 0);
  }

#pragma unroll
  for (int rt = 0; rt < 5; ++rt)
#pragma unroll
    for (int r = 0; r < 4; ++r) {
      const int gr = w * 80 + rt * 16 + 4 * l4 + r;
      const float bias = (gr < 32) ? bq[gr] : (gr < 64) ? bk[gr - 32] : bv[gr - 64];
#pragma unroll
      for (int ct = 0; ct < 4; ++ct) {
        const int n = n0 + ct * 16 + lm;
        float v = acc[rt][ct][r] + bias;
        if (gr < 32) {
          v *= 1.44269504088896f;
          Qh[((size_t)(b * N_ + n)) * D_ + gr] = (bf16_t)v;
        } else if (gr < 64) {
          Kh[((size_t)(b * N_ + n)) * D_ + (gr - 32)] = (bf16_t)v;
        } else {
          Vh[((size_t)(b * C_ + (gr - 64))) * N_ + n] = (bf16_t)v;
        }
      }
    }
}

// ---------------------------------------------------------------------------
// Flash attention, K-SPLIT blocks (2 blocks/CU, 16 waves/CU): grid 512 =
// (batch, q-tile 64, key-half 2048). Per-iter structure identical to the
// 74.8us R8 kernel; per-CU traffic totals unchanged; TLP doubled.
// Fixed-reference exp2 softmax -> partials combine by simple weighted sum.
// Block emits o_part = acc/l_part (bf16) + l_part; combine kernel finishes.
// XCD mapping: xcd = 2*batch + khalf -> each XCD's K/V slice 1.1MB L2-hot.
// ---------------------------------------------------------------------------
__global__ __launch_bounds__(512, 4) void attn_kernel(
    const bf16_t* __restrict__ Qh, const bf16_t* __restrict__ Kh,
    const bf16_t* __restrict__ Vh,
    bf16_t* __restrict__ opart, float* __restrict__ lpart)
{
  __shared__ __align__(16) bf16_t Pl[2][64][KT];  // 64 KB double-buffered P
  __shared__ __align__(16) float  Lx[64][12];     // epilogue l exchange

  const int bi = blockIdx.x;
  const int xcd = bi & 7;
  const int b  = xcd >> 1;
  const int kh = xcd & 1;                  // key half
  const int qt = bi >> 3;                  // 0..63
  const int q0 = qt * 64;

  const int t = threadIdx.x, w = t >> 6, lane = t & 63;
  const int l4 = lane >> 4, lm = lane & 15;
  const int swz = (lm & 7) << 3;

  const f32x4 z4 = {0.f, 0.f, 0.f, 0.f};

  // Q fragments: 4 q-subtiles of 16 (held whole kernel)
  bf16x8_t qf[4];
#pragma unroll
  for (int rt = 0; rt < 4; ++rt)
    qf[rt] = *(const bf16x8_t*)(Qh + ((size_t)(b * N_ + q0 + rt * 16 + lm)) * D_ + l4 * 8);

  const bf16_t* kbase = Kh + ((size_t)(b * N_ + kh * KH + w * 32 + lm)) * D_ + l4 * 8;
  const bf16_t* vbase = Vh + ((size_t)(b * C_ + w * 32 + lm)) * N_ + kh * KH + l4 * 8;

  f32x4 acc[2][4];   // [ct][rt] : 32 ch x 64 q
#pragma unroll
  for (int ct = 0; ct < 2; ++ct)
#pragma unroll
    for (int rt = 0; rt < 4; ++rt) acc[ct][rt] = z4;
  float l_run[4] = {0.f, 0.f, 0.f, 0.f};   // lane-local partial denominators

  // prologue: K tile 0; V fragments for substeps 0 and 1
  bf16x8_t kf[2], kn[2];
#pragma unroll
  for (int mt = 0; mt < 2; ++mt)
    kf[mt] = *(const bf16x8_t*)(kbase + (size_t)(mt * 16) * D_);
  bf16x8_t vf0[2][2], vf1[2][2];
#pragma unroll
  for (int ct = 0; ct < 2; ++ct)
#pragma unroll
    for (int kc = 0; kc < 2; ++kc) {
      vf0[ct][kc] = *(const bf16x8_t*)(vbase + (size_t)(ct * 16) * N_ + kc * 32);
      vf1[ct][kc] = *(const bf16x8_t*)(vbase + (size_t)(ct * 16) * N_ + 64 + kc * 32);
    }

#pragma unroll 1
  for (int it = 0; it < KH / KT; ++it) {
    const int buf = it & 1;

    // ---- S: 64 q x this wave's 32 keys ----
    f32x4 S[4][2];
#pragma unroll
    for (int rt = 0; rt < 4; ++rt)
#pragma unroll
      for (int mt = 0; mt < 2; ++mt)
        S[rt][mt] = __builtin_amdgcn_mfma_f32_16x16x32_bf16(kf[mt], qf[rt], z4, 0, 0, 0);

    // prefetch next iter's K slice
    const int k0n = ((it + 1) * KT) & (KH - 1);
#pragma unroll
    for (int mt = 0; mt < 2; ++mt)
      kn[mt] = *(const bf16x8_t*)(kbase + (size_t)(k0n + mt * 16) * D_);

    // ---- p = exp2(S) (fixed reference 0), P write, local l acc ----
#pragma unroll
    for (int rt = 0; rt < 4; ++rt) {
      const int prow = rt * 16 + lm;
#pragma unroll
      for (int mt = 0; mt < 2; ++mt) {
        const float p0 = __builtin_amdgcn_exp2f(S[rt][mt][0]);
        const float p1 = __builtin_amdgcn_exp2f(S[rt][mt][1]);
        const float p2 = __builtin_amdgcn_exp2f(S[rt][mt][2]);
        const float p3 = __builtin_amdgcn_exp2f(S[rt][mt][3]);
        l_run[rt] += (p0 + p1) + (p2 + p3);
        bf16x4_t w4 = {(bf16_t)p0, (bf16_t)p1, (bf16_t)p2, (bf16_t)p3};
        *(bf16x4_t*)&Pl[buf][prow][(w * 32 + mt * 16 + 4 * l4) ^ swz] = w4;
      }
    }

    asm volatile("s_waitcnt lgkmcnt(0)" ::: "memory");   // P visible; prev reads drained
    __builtin_amdgcn_s_barrier();

    // ---- PV: 4 barrier-free substeps x 64 keys; V depth-2 reg prefetch ----
#pragma unroll
    for (int s4 = 0; s4 < 4; ++s4) {
      bf16x8_t pa[4][2];
#pragma unroll
      for (int rt = 0; rt < 4; ++rt)
#pragma unroll
        for (int kc = 0; kc < 2; ++kc)
          pa[rt][kc] = *(const bf16x8_t*)&Pl[buf][rt * 16 + lm][(s4 * 64 + kc * 32 + l4 * 8) ^ swz];
      const int knx = (it * KT + (s4 + 2) * 64) & (KH - 1);
      if ((s4 & 1) == 0) {
#pragma unroll
        for (int ct = 0; ct < 2; ++ct)
#pragma unroll
          for (int kc = 0; kc < 2; ++kc)
#pragma unroll
            for (int rt = 0; rt < 4; ++rt)
              acc[ct][rt] = __builtin_amdgcn_mfma_f32_16x16x32_bf16(vf0[ct][kc], pa[rt][kc], acc[ct][rt], 0, 0, 0);
#pragma unroll
        for (int ct = 0; ct < 2; ++ct)
#pragma unroll
          for (int kc = 0; kc < 2; ++kc)
            vf0[ct][kc] = *(const bf16x8_t*)(vbase + (size_t)(ct * 16) * N_ + knx + kc * 32);
      } else {
#pragma unroll
        for (int ct = 0; ct < 2; ++ct)
#pragma unroll
          for (int kc = 0; kc < 2; ++kc)
#pragma unroll
            for (int rt = 0; rt < 4; ++rt)
              acc[ct][rt] = __builtin_amdgcn_mfma_f32_16x16x32_bf16(vf1[ct][kc], pa[rt][kc], acc[ct][rt], 0, 0, 0);
#pragma unroll
        for (int ct = 0; ct < 2; ++ct)
#pragma unroll
          for (int kc = 0; kc < 2; ++kc)
            vf1[ct][kc] = *(const bf16x8_t*)(vbase + (size_t)(ct * 16) * N_ + knx + kc * 32);
      }
    }

#pragma unroll
    for (int mt = 0; mt < 2; ++mt) kf[mt] = kn[mt];
  }

  // ---- epilogue: reduce l, write partial o (bf16) and l ----
#pragma unroll
  for (int rt = 0; rt < 4; ++rt) {
    l_run[rt] += __shfl_xor(l_run[rt], 16);
    l_run[rt] += __shfl_xor(l_run[rt], 32);
  }
  if (l4 == 0) {
#pragma unroll
    for (int rt = 0; rt < 4; ++rt) Lx[rt * 16 + lm][w] = l_run[rt];
  }
  asm volatile("s_waitcnt lgkmcnt(0)" ::: "memory");
  __builtin_amdgcn_s_barrier();

  const int blk = xcd * 64 + qt;
  bf16_t* oblk = opart + (size_t)blk * (C_ * 64);
#pragma unroll
  for (int rt = 0; rt < 4; ++rt) {
    const f32x4 s0 = *(const f32x4*)&Lx[rt * 16 + lm][0];
    const f32x4 s1 = *(const f32x4*)&Lx[rt * 16 + lm][4];
    const float lt = ((s0[0] + s0[1]) + (s0[2] + s0[3])) + ((s1[0] + s1[1]) + (s1[2] + s1[3]));
    const float inv = 1.f / lt;
    const int nl = rt * 16 + lm;
    if (w == 0 && l4 == 0) lpart[blk * 64 + nl] = lt;
#pragma unroll
    for (int ct = 0; ct < 2; ++ct) {
#pragma unroll
      for (int r = 0; r < 4; ++r) {
        const int c = w * 32 + ct * 16 + 4 * l4 + r;
        oblk[c * 64 + nl] = (bf16_t)(acc[ct][rt][r] * inv);
      }
    }
  }
}

// ---------------------------------------------------------------------------
// combine: out = gamma * (lA*oA + lB*oB)/(lA+lB) + x.  8 elems/thread.
// ---------------------------------------------------------------------------
__global__ __launch_bounds__(256) void combine_kernel(
    const bf16_t* __restrict__ opart, const float* __restrict__ lpart,
    const float* __restrict__ x, const float* __restrict__ gamma,
    float* __restrict__ out)
{
  const int g  = blockIdx.x * 256 + threadIdx.x;
  const int e  = g * 8;
  const int b  = e >> 20;
  const int c  = (e >> 12) & 255;
  const int n  = e & 4095;
  const int qt = n >> 6;
  const int nl = n & 63;
  const int blkA = (b * 2) * 64 + qt;
  const int blkB = blkA + 64;

  const bf16x8_t oA = *(const bf16x8_t*)(opart + (size_t)blkA * (C_ * 64) + c * 64 + nl);
  const bf16x8_t oB = *(const bf16x8_t*)(opart + (size_t)blkB * (C_ * 64) + c * 64 + nl);
  const f32x4 lA0 = *(const f32x4*)(lpart + blkA * 64 + nl);
  const f32x4 lA1 = *(const f32x4*)(lpart + blkA * 64 + nl + 4);
  const f32x4 lB0 = *(const f32x4*)(lpart + blkB * 64 + nl);
  const f32x4 lB1 = *(const f32x4*)(lpart + blkB * 64 + nl + 4);
  const float gm = gamma[0];

  const f32x4 xv0 = *(const f32x4*)(x + e);
  const f32x4 xv1 = *(const f32x4*)(x + e + 4);
  f32x4 o0, o1;
#pragma unroll
  for (int j = 0; j < 4; ++j) {
    const float la = lA0[j], lb = lB0[j];
    o0[j] = gm * ((la * (float)oA[j] + lb * (float)oB[j]) / (la + lb)) + xv0[j];
  }
#pragma unroll
  for (int j = 0; j < 4; ++j) {
    const float la = lA1[j], lb = lB1[j];
    o1[j] = gm * ((la * (float)oA[4 + j] + lb * (float)oB[4 + j]) / (la + lb)) + xv1[j];
  }
  *(f32x4*)(out + e)     = o0;
  *(f32x4*)(out + e + 4) = o1;
}

extern "C" void kernel_launch(void* const* d_in, const int* in_sizes, int n_in,
                              void* d_out, int out_size, void* d_ws, size_t ws_size,
                              hipStream_t stream) {
  const float* x     = (const float*)d_in[0];
  const float* wq    = (const float*)d_in[1];
  const float* bq    = (const float*)d_in[2];
  const float* wk    = (const float*)d_in[3];
  const float* bk    = (const float*)d_in[4];
  const float* wv    = (const float*)d_in[5];
  const float* bv    = (const float*)d_in[6];
  const float* gamma = (const float*)d_in[7];
  float* out = (float*)d_out;

  // ws: Qh 1MB | Kh 1MB | Vh 8MB | Wb 160KB | xbT 8MB | opart 16.8MB | lpart 128KB
  bf16_t* Qh    = (bf16_t*)d_ws;
  bf16_t* Kh    = Qh + (size_t)B_ * N_ * D_;
  bf16_t* Vh    = Kh + (size_t)B_ * N_ * D_;
  bf16_t* Wb    = Vh + (size_t)B_ * C_ * N_;
  bf16_t* xbT   = Wb + (size_t)320 * C_;
  bf16_t* opart = xbT + (size_t)B_ * N_ * C_;
  float*  lpart = (float*)(opart + (size_t)512 * C_ * 64);

  cast_kernel<<<1344, 256, 0, stream>>>(x, wq, wk, wv, xbT, Wb);
  proj_kernel<<<256, 256, 0, stream>>>(Wb, xbT, bq, bk, bv, Qh, Kh, Vh);
  attn_kernel<<<512, 512, 0, stream>>>(Qh, Kh, Vh, opart, lpart);
  combine_kernel<<<2048, 256, 0, stream>>>(opart, lpart, x, gamma, out);
}

// Round 12
// 92.936 us; speedup vs baseline: 1.4299x; 1.4299x over previous
//
#include <hip/hip_runtime.h>
#include <hip/hip_bf16.h>
#include <stdint.h>

#define B_ 4
#define C_ 256
#define N_ 4096
#define D_ 32
#define KT 512   // keys per outer iteration (8 iters total)

typedef __bf16 bf16_t;
typedef __bf16 bf16x4_t __attribute__((ext_vector_type(4)));
typedef __bf16 bf16x8_t __attribute__((ext_vector_type(8)));
typedef float  f32x4    __attribute__((ext_vector_type(4)));

// ---------------------------------------------------------------------------
// cast W (wq|wk|wv) -> Wb bf16 [320][256]
// ---------------------------------------------------------------------------
__global__ __launch_bounds__(256) void cast_w_kernel(
    const float* __restrict__ wq, const float* __restrict__ wk,
    const float* __restrict__ wv, bf16_t* __restrict__ Wb)
{
  const int gr = blockIdx.x;
  const int t  = threadIdx.x;
  float v;
  if (gr < 32)      v = wq[gr * C_ + t];
  else if (gr < 64) v = wk[(gr - 32) * C_ + t];
  else              v = wv[(gr - 64) * C_ + t];
  Wb[gr * C_ + t] = (bf16_t)v;
}

// ---------------------------------------------------------------------------
// Projection GEMM with FUSED transpose: reads x f32 directly (no xbT pass).
// Per k-tile: stage x[b][k0:+64][n0:+64] f32 in LDS [64][65] (coalesced
// f32x4 row loads; column fragment reads are 2-way max), cvt to bf16 at
// fragment build. grid 256, n-tile 64. Q pre-scaled by log2(e).
// ---------------------------------------------------------------------------
__global__ __launch_bounds__(256) void proj_kernel(
    const float* __restrict__ x, const bf16_t* __restrict__ Wb,
    const float* __restrict__ bq, const float* __restrict__ bk,
    const float* __restrict__ bv,
    bf16_t* __restrict__ Qh, bf16_t* __restrict__ Kh, bf16_t* __restrict__ Vh)
{
  __shared__ float xs[64][65];
  const int bi = blockIdx.x;
  const int b  = bi & 3;
  const int n0 = (bi >> 2) * 64;
  const int t = threadIdx.x, w = t >> 6, lane = t & 63;
  const int l4 = lane >> 4, lm = lane & 15;

  const f32x4 z4 = {0.f, 0.f, 0.f, 0.f};
  f32x4 acc[5][4];
#pragma unroll
  for (int rt = 0; rt < 5; ++rt)
#pragma unroll
    for (int ct = 0; ct < 4; ++ct) acc[rt][ct] = z4;

  const int lr = t >> 2;          // x row within k-tile (0..63)
  const int lc = (t & 3) * 16;    // col base (0,16,32,48)

#pragma unroll 1
  for (int k0 = 0; k0 < C_; k0 += 64) {
    __syncthreads();   // previous tile's readers done
#pragma unroll
    for (int i = 0; i < 4; ++i) {
      const f32x4 v = *(const f32x4*)(x + ((size_t)(b * C_ + k0 + lr)) * N_ + n0 + lc + i * 4);
      xs[lr][lc + i * 4 + 0] = v[0];
      xs[lr][lc + i * 4 + 1] = v[1];
      xs[lr][lc + i * 4 + 2] = v[2];
      xs[lr][lc + i * 4 + 3] = v[3];
    }
    __syncthreads();

    bf16x8_t af[5][2], bfr[4][2];
#pragma unroll
    for (int rt = 0; rt < 5; ++rt)
#pragma unroll
      for (int kc = 0; kc < 2; ++kc)
        af[rt][kc] = *(const bf16x8_t*)(Wb + (size_t)(w * 80 + rt * 16 + lm) * C_ + k0 + kc * 32 + l4 * 8);
#pragma unroll
    for (int ct = 0; ct < 4; ++ct)
#pragma unroll
      for (int kc = 0; kc < 2; ++kc) {
        bf16_t tmp[8];
#pragma unroll
        for (int j = 0; j < 8; ++j)
          tmp[j] = (bf16_t)xs[kc * 32 + l4 * 8 + j][ct * 16 + lm];
        bfr[ct][kc] = *(bf16x8_t*)tmp;
      }
#pragma unroll
    for (int rt = 0; rt < 5; ++rt)
#pragma unroll
      for (int ct = 0; ct < 4; ++ct)
#pragma unroll
        for (int kc = 0; kc < 2; ++kc)
          acc[rt][ct] = __builtin_amdgcn_mfma_f32_16x16x32_bf16(af[rt][kc], bfr[ct][kc], acc[rt][ct], 0, 0, 0);
  }

#pragma unroll
  for (int rt = 0; rt < 5; ++rt)
#pragma unroll
    for (int r = 0; r < 4; ++r) {
      const int gr = w * 80 + rt * 16 + 4 * l4 + r;
      const float bias = (gr < 32) ? bq[gr] : (gr < 64) ? bk[gr - 32] : bv[gr - 64];
#pragma unroll
      for (int ct = 0; ct < 4; ++ct) {
        const int n = n0 + ct * 16 + lm;
        float v = acc[rt][ct][r] + bias;
        if (gr < 32) {
          v *= 1.44269504088896f;
          Qh[((size_t)(b * N_ + n)) * D_ + gr] = (bf16_t)v;
        } else if (gr < 64) {
          Kh[((size_t)(b * N_ + n)) * D_ + (gr - 32)] = (bf16_t)v;
        } else {
          Vh[((size_t)(b * C_ + (gr - 64))) * N_ + n] = (bf16_t)v;
        }
      }
    }
}

// ---------------------------------------------------------------------------
// Flash attention, fixed-reference exp2 softmax, KT=512 (8 iters, 8 barrier
// drains instead of 16 — attacks the per-iteration lockstep overhead).
// 8 waves = 8 ch-groups x 32 ch, each spans all 64 q; keys split 8-way
// (wave owns 64 keys/iter). P double-buffered 2x64KB; ONE lgkm-only barrier
// per iter; l lane-local. V/K direct from L2, depth-2 / 1-iter reg prefetch.
// ---------------------------------------------------------------------------
__global__ __launch_bounds__(512, 2) void attn_kernel(
    const bf16_t* __restrict__ Qh, const bf16_t* __restrict__ Kh,
    const bf16_t* __restrict__ Vh, const float* __restrict__ x,
    const float* __restrict__ gamma, float* __restrict__ out)
{
  __shared__ __align__(16) bf16_t Pl[2][64][KT];  // 128 KB double-buffered P
  __shared__ __align__(16) float  Lx[64][12];     // epilogue l exchange

  const int bi = blockIdx.x;
  const int xcd = bi & 7, slot = bi >> 3;
  const int b  = xcd >> 1;                 // 2 XCDs per batch -> K,V,Q L2-resident
  const int q0 = ((xcd & 1) * 32 + slot) * 64;

  const int t = threadIdx.x, w = t >> 6, lane = t & 63;
  const int l4 = lane >> 4, lm = lane & 15;
  const int swz = (lm & 7) << 3;

  const f32x4 z4 = {0.f, 0.f, 0.f, 0.f};

  // Q fragments: 4 q-subtiles of 16 (held whole kernel)
  bf16x8_t qf[4];
#pragma unroll
  for (int rt = 0; rt < 4; ++rt)
    qf[rt] = *(const bf16x8_t*)(Qh + ((size_t)(b * N_ + q0 + rt * 16 + lm)) * D_ + l4 * 8);

  const bf16_t* kbase = Kh + ((size_t)(b * N_ + w * 64 + lm)) * D_ + l4 * 8;
  const bf16_t* vbase = Vh + ((size_t)(b * C_ + w * 32 + lm)) * N_ + l4 * 8;

  f32x4 acc[2][4];   // [ct][rt] : 32 ch x 64 q
#pragma unroll
  for (int ct = 0; ct < 2; ++ct)
#pragma unroll
    for (int rt = 0; rt < 4; ++rt) acc[ct][rt] = z4;
  float l_run[4] = {0.f, 0.f, 0.f, 0.f};   // lane-local partial denominators

  // prologue: K tile 0 (wave's 64-key slice); V fragments for substeps 0/1
  bf16x8_t kf[4], kn[4];
#pragma unroll
  for (int mt = 0; mt < 4; ++mt)
    kf[mt] = *(const bf16x8_t*)(kbase + (size_t)(mt * 16) * D_);
  bf16x8_t vf0[2][2], vf1[2][2];
#pragma unroll
  for (int ct = 0; ct < 2; ++ct)
#pragma unroll
    for (int kc = 0; kc < 2; ++kc) {
      vf0[ct][kc] = *(const bf16x8_t*)(vbase + (size_t)(ct * 16) * N_ + kc * 32);
      vf1[ct][kc] = *(const bf16x8_t*)(vbase + (size_t)(ct * 16) * N_ + 64 + kc * 32);
    }

#pragma unroll 1
  for (int it = 0; it < N_ / KT; ++it) {
    const int buf = it & 1;

    // ---- S: 64 q x this wave's 64 keys ----
    f32x4 S[4][4];
#pragma unroll
    for (int rt = 0; rt < 4; ++rt)
#pragma unroll
      for (int mt = 0; mt < 4; ++mt)
        S[rt][mt] = __builtin_amdgcn_mfma_f32_16x16x32_bf16(kf[mt], qf[rt], z4, 0, 0, 0);

    // prefetch next iter's K slice (in flight across exp2+PV)
    const int k0n = ((it + 1) * KT) & (N_ - 1);
#pragma unroll
    for (int mt = 0; mt < 4; ++mt)
      kn[mt] = *(const bf16x8_t*)(kbase + (size_t)(k0n + mt * 16) * D_);

    // ---- p = exp2(S) (fixed reference 0), P write, local l acc ----
#pragma unroll
    for (int rt = 0; rt < 4; ++rt) {
      const int prow = rt * 16 + lm;
#pragma unroll
      for (int mt = 0; mt < 4; ++mt) {
        const float p0 = __builtin_amdgcn_exp2f(S[rt][mt][0]);
        const float p1 = __builtin_amdgcn_exp2f(S[rt][mt][1]);
        const float p2 = __builtin_amdgcn_exp2f(S[rt][mt][2]);
        const float p3 = __builtin_amdgcn_exp2f(S[rt][mt][3]);
        l_run[rt] += (p0 + p1) + (p2 + p3);
        bf16x4_t w4 = {(bf16_t)p0, (bf16_t)p1, (bf16_t)p2, (bf16_t)p3};
        *(bf16x4_t*)&Pl[buf][prow][(w * 64 + mt * 16 + 4 * l4) ^ swz] = w4;
      }
    }

    asm volatile("s_waitcnt lgkmcnt(0)" ::: "memory");   // P visible; prev reads drained
    __builtin_amdgcn_s_barrier();

    // ---- PV: 8 barrier-free substeps x 64 keys; V depth-2 reg prefetch ----
#pragma unroll
    for (int s4 = 0; s4 < 8; ++s4) {
      bf16x8_t pa[4][2];
#pragma unroll
      for (int rt = 0; rt < 4; ++rt)
#pragma unroll
        for (int kc = 0; kc < 2; ++kc)
          pa[rt][kc] = *(const bf16x8_t*)&Pl[buf][rt * 16 + lm][(s4 * 64 + kc * 32 + l4 * 8) ^ swz];
      const int knx = (it * KT + (s4 + 2) * 64) & (N_ - 1);
      if ((s4 & 1) == 0) {
#pragma unroll
        for (int ct = 0; ct < 2; ++ct)
#pragma unroll
          for (int kc = 0; kc < 2; ++kc)
#pragma unroll
            for (int rt = 0; rt < 4; ++rt)
              acc[ct][rt] = __builtin_amdgcn_mfma_f32_16x16x32_bf16(vf0[ct][kc], pa[rt][kc], acc[ct][rt], 0, 0, 0);
#pragma unroll
        for (int ct = 0; ct < 2; ++ct)
#pragma unroll
          for (int kc = 0; kc < 2; ++kc)
            vf0[ct][kc] = *(const bf16x8_t*)(vbase + (size_t)(ct * 16) * N_ + knx + kc * 32);
      } else {
#pragma unroll
        for (int ct = 0; ct < 2; ++ct)
#pragma unroll
          for (int kc = 0; kc < 2; ++kc)
#pragma unroll
            for (int rt = 0; rt < 4; ++rt)
              acc[ct][rt] = __builtin_amdgcn_mfma_f32_16x16x32_bf16(vf1[ct][kc], pa[rt][kc], acc[ct][rt], 0, 0, 0);
#pragma unroll
        for (int ct = 0; ct < 2; ++ct)
#pragma unroll
          for (int kc = 0; kc < 2; ++kc)
            vf1[ct][kc] = *(const bf16x8_t*)(vbase + (size_t)(ct * 16) * N_ + knx + kc * 32);
      }
    }

#pragma unroll
    for (int mt = 0; mt < 4; ++mt) kf[mt] = kn[mt];
  }

  // ---- epilogue: reduce l (lane-local -> per-q -> cross-wave), then store ----
#pragma unroll
  for (int rt = 0; rt < 4; ++rt) {
    l_run[rt] += __shfl_xor(l_run[rt], 16);
    l_run[rt] += __shfl_xor(l_run[rt], 32);
  }
  if (l4 == 0) {
#pragma unroll
    for (int rt = 0; rt < 4; ++rt) Lx[rt * 16 + lm][w] = l_run[rt];
  }
  asm volatile("s_waitcnt lgkmcnt(0)" ::: "memory");
  __builtin_amdgcn_s_barrier();

  const float g = gamma[0];
#pragma unroll
  for (int rt = 0; rt < 4; ++rt) {
    const f32x4 s0 = *(const f32x4*)&Lx[rt * 16 + lm][0];
    const f32x4 s1 = *(const f32x4*)&Lx[rt * 16 + lm][4];
    const float lt = ((s0[0] + s0[1]) + (s0[2] + s0[3])) + ((s1[0] + s1[1]) + (s1[2] + s1[3]));
    const float inv = 1.f / lt;
    const int n = q0 + rt * 16 + lm;
#pragma unroll
    for (int ct = 0; ct < 2; ++ct) {
#pragma unroll
      for (int r = 0; r < 4; ++r) {
        const int c = w * 32 + ct * 16 + 4 * l4 + r;
        const size_t idx = ((size_t)(b * C_ + c)) * N_ + n;
        out[idx] = g * (acc[ct][rt][r] * inv) + x[idx];
      }
    }
  }
}

extern "C" void kernel_launch(void* const* d_in, const int* in_sizes, int n_in,
                              void* d_out, int out_size, void* d_ws, size_t ws_size,
                              hipStream_t stream) {
  const float* x     = (const float*)d_in[0];
  const float* wq    = (const float*)d_in[1];
  const float* bq    = (const float*)d_in[2];
  const float* wk    = (const float*)d_in[3];
  const float* bk    = (const float*)d_in[4];
  const float* wv    = (const float*)d_in[5];
  const float* bv    = (const float*)d_in[6];
  const float* gamma = (const float*)d_in[7];
  float* out = (float*)d_out;

  // ws: Qh 1MB | Kh 1MB | Vh 8MB | Wb 160KB
  bf16_t* Qh = (bf16_t*)d_ws;
  bf16_t* Kh = Qh + (size_t)B_ * N_ * D_;
  bf16_t* Vh = Kh + (size_t)B_ * N_ * D_;
  bf16_t* Wb = Vh + (size_t)B_ * C_ * N_;

  cast_w_kernel<<<320, 256, 0, stream>>>(wq, wk, wv, Wb);
  proj_kernel<<<256, 256, 0, stream>>>(x, Wb, bq, bk, bv, Qh, Kh, Vh);
  attn_kernel<<<256, 512, 0, stream>>>(Qh, Kh, Vh, x, gamma, out);
}